// Round 2
// baseline (271.302 us; speedup 1.0000x reference)
//
#include <hip/hip_runtime.h>

// CausalSelfAttention: x[4,2048,1024] fp32 -> out fp32
// Pipeline (all bf16 MFMA, fp32 accum):
//  1) cvt x -> bf16            2) transpose+cvt W_attn & W_proj -> bf16 [N][K]
//  3) gemm8p<0,4> (256x256 tile, BK=32, 2-phase/tile counted-vmcnt schedule)
//     -> Q (pre-scaled by 0.125*log2e), K, V TRANSPOSED [b,h,d,s] (scatter)
//  4) flash attention: 128 q-rows/block (4 waves x 32), XCD head-affinity
//     swizzle, fixed-max softmax (P = 2^s), K/Vt direct-to-LDS w/ XOR swizzle.
//  5) gemm8p<1,2> (256x128 tile) + bias -> out fp32
//
// R2 NOTE: R1 died in harness (container fail x2) -> attributed to
// hipFuncSetAttribute inside kernel_launch (graph-capture-illegal host call)
// + >64KB dynamic LDS depending on it. This version: NO host API calls, all
// LDS static and <=64KB. Phase schedule (the actual R0 theory) preserved:
//  - 8 waves (2M x 4N), per-wave 128 x NF*16 out, acc[8][NF] f32x4
//  - LDS: A[2][256][32] (32KB) + B[2][BN][32] bf16, chunk-XOR swizzle
//    (slot u holds global chunk u^(row&3); reader XORs back) -> conflict-free
//  - per K-tile (32): P0 {RD_A x8, RD_B lo, issue A1/B0[/B1](t+1), BAR,
//    setprio1, 16 MFMA, setprio0, BAR}  P1 {RD_B hi, issue A0(t+2),
//    vmcnt(1), BAR, setprio1, 16 MFMA, setprio0, BAR}
//  - vmcnt(1) once per tile, NEVER 0 in the loop (A0(t+2) stays in flight
//    across the barrier = counted-vmcnt pipeline, guide T3+T4)
//  - overwrite safety: every ds_read is consumed by an MFMA in its own phase
//    (compiler lgkmcnt) -> completed before that phase's trailing barrier;
//    all prefetch issues happen in a later phase. A0(t+2) targets the
//    current A buffer rows 0-127, whose reads all complete in P0.
//  - tail: issues clamped to last tile (dummy identical-data re-loads) so
//    per-wave vmcnt counting stays uniform; vmcnt(0) drain after loop.
// MFMA 16x16x32 bf16 layouts (HW-verified per guide):
//   A: a[j] = A[m=lane&15][k=quad*8+j]  (quad=lane>>4)
//   B: b[j] = B[k=quad*8+j][n=lane&15]  (from Bt[n][k] read at row n)
//   C/D: c[i] = D[row=quad*4+i][col=lane&15]

#define BATCH 4
#define SEQ   2048
#define EMB   1024
#define NH    16
#define HD    64

typedef __bf16 bf16;
typedef __bf16 bf16x8 __attribute__((ext_vector_type(8)));
typedef float  f32x4  __attribute__((ext_vector_type(4)));

// direct global->LDS 16B copy: LDS dest is wave-uniform base + lane*16
__device__ __forceinline__ void ld_lds16(const void* g, void* l) {
  __builtin_amdgcn_global_load_lds(
      (const __attribute__((address_space(1))) void*)g,
      (__attribute__((address_space(3))) void*)l, 16, 0, 0);
}

// ---------------- convert fp32 -> bf16 ----------------
__global__ void cvt_f32_bf16(const float* __restrict__ in, bf16* __restrict__ out, int n) {
  int i = (blockIdx.x * blockDim.x + threadIdx.x) * 4;
  if (i + 3 < n) {
    float4 v = *(const float4*)(in + i);
    bf16 o0 = (bf16)v.x, o1 = (bf16)v.y, o2 = (bf16)v.z, o3 = (bf16)v.w;
    out[i] = o0; out[i+1] = o1; out[i+2] = o2; out[i+3] = o3;
  }
}

// ---------------- transpose + convert both weights (one launch) ----------------
__global__ void transpose_cvt2(const float* __restrict__ Wa, const float* __restrict__ Wp,
                               bf16* __restrict__ WaT, bf16* __restrict__ WpT) {
  __shared__ float tile[32][33];
  int bx = blockIdx.x;
  const float* W; bf16* WT; int N;
  if (bx < 96) { W = Wa; WT = WaT; N = 3072; }
  else         { W = Wp; WT = WpT; N = 1024; bx -= 96; }
  int n0 = bx * 32, k0 = blockIdx.y * 32;
  int tx = threadIdx.x & 31, ty = threadIdx.x >> 5;
#pragma unroll
  for (int r = 0; r < 4; r++) {
    int k = k0 + ty + r * 8;
    tile[ty + r * 8][tx] = W[(long)k * N + n0 + tx];
  }
  __syncthreads();
#pragma unroll
  for (int r = 0; r < 4; r++) {
    int n = n0 + ty + r * 8;
    WT[(long)n * EMB + k0 + tx] = (bf16)tile[tx][ty + r * 8];
  }
}

#define QSCALE 0.18033688f   // (1/8) * log2(e)

// ---------------- 256xBN phase-pipelined GEMM ----------------
// A[M][1024] bf16 x Bt[N][1024] bf16 + bias. BN = NF*64.
// MODE 0 (NF=4, grid 384): QKV split write (Q scaled, V scatter-transposed).
// MODE 1 (NF=2, grid 256): f32 out.
template <int MODE, int NF>
__global__ __launch_bounds__(512, 2) void gemm8p(
    const bf16* __restrict__ A, const bf16* __restrict__ Bt,
    const float* __restrict__ bias,
    bf16* __restrict__ q, bf16* __restrict__ k, bf16* __restrict__ v,
    float* __restrict__ out)
{
  constexpr int BN = NF * 64;        // block N extent
  constexpr int WN = NF * 16;        // per-wave N extent
  constexpr int BELEM = BN * 32;     // B buffer elems
  __shared__ __align__(16) bf16 lds[16384 + 2 * BELEM];   // <= 64KB static
  int lin = blockIdx.x;
  int xcd = lin & 7, s = lin >> 3;
  int by = xcd * 4 + (s & 3);        // XCD-affine row strips
  int bx = s >> 2;
  int m0 = by * 256, n0 = bx * BN;
  int t = threadIdx.x;
  int wid = t >> 6, lane = t & 63;
  int l15 = lane & 15, quad = lane >> 4;
  int wr = wid >> 2, wc = wid & 3;   // wave tile: rows wr*128.., cols wc*WN..

  const bf16* Ag = A + (long)m0 * EMB;
  const bf16* Bg = Bt + (long)n0 * EMB;

  f32x4 acc[8][NF] = {};
  bf16x8 af[8], bfr[NF];
  constexpr int NT = EMB / 32;       // 32 K-tiles

#define LDSA(b) (lds + (b) * 8192)
#define LDSB(b) (lds + 16384 + (b) * BELEM)

  // stage a 128-row x 32-col half-tile: 1 gload_lds per thread.
  // LDS dest linear; source chunk pre-swizzled: slot u <- chunk u^(row&3).
#define ISSUE128(gbase, rowoff, ldst, ktt)                                     \
  { int r_ = (rowoff) + (t >> 2);                                              \
    ld_lds16(&(gbase)[(long)r_ * EMB + (ktt) + (((t & 3) ^ (r_ & 3)) * 8)],    \
             (ldst) + ((rowoff) + wid * 16) * 32); }

#define RD_A(mi) { int r_ = wr * 128 + (mi) * 16 + l15;                        \
    af[mi] = *(const bf16x8*)&Ab[r_ * 32 + ((quad ^ (r_ & 3)) * 8)]; }
#define RD_B(ni) { int r_ = wc * WN + (ni) * 16 + l15;                         \
    bfr[ni] = *(const bf16x8*)&Bb[r_ * 32 + ((quad ^ (r_ & 3)) * 8)]; }

#define FENCE asm volatile("" ::: "memory")
#define BAR   { FENCE; __builtin_amdgcn_s_barrier(); FENCE; }

#define MFMAC(nlo)                                                             \
  { __builtin_amdgcn_s_setprio(1);                                             \
    _Pragma("unroll") for (int mi_ = 0; mi_ < 8; ++mi_)                        \
      _Pragma("unroll") for (int nj_ = 0; nj_ < NF / 2; ++nj_)                 \
        acc[mi_][(nlo) + nj_] = __builtin_amdgcn_mfma_f32_16x16x32_bf16(       \
            af[mi_], bfr[(nlo) + nj_], acc[mi_][(nlo) + nj_], 0, 0, 0);        \
    __builtin_amdgcn_s_setprio(0); }

  // prologue: tile0 complete + A-half0(tile1) in flight
  ISSUE128(Ag, 0,   LDSA(0), 0);
  ISSUE128(Ag, 128, LDSA(0), 0);
  ISSUE128(Bg, 0,   LDSB(0), 0);
  if constexpr (NF == 4) ISSUE128(Bg, 128, LDSB(0), 0);
  ISSUE128(Ag, 0,   LDSA(1), 32);
  asm volatile("s_waitcnt vmcnt(1)" ::: "memory");
  BAR;

#pragma unroll 2
  for (int tt = 0; tt < NT; ++tt) {
    const bf16* Ab = LDSA(tt & 1);
    const bf16* Bb = LDSB(tt & 1);
    bf16* An = LDSA((tt + 1) & 1);
    bf16* Bn = LDSB((tt + 1) & 1);
    bf16* Ac = LDSA(tt & 1);                         // A0(t+2): (tt+2)&1==tt&1
    int kn  = (tt + 1 < NT ? tt + 1 : NT - 1) * 32;  // clamped at tail:
    int kn2 = (tt + 2 < NT ? tt + 2 : NT - 1) * 32;  // dummy identical reload

    // P0: all A frags + low B frags; prefetch A1/B0[/B1](t+1) (other buffer)
#pragma unroll
    for (int mi = 0; mi < 8; ++mi) RD_A(mi);
#pragma unroll
    for (int ni = 0; ni < NF / 2; ++ni) RD_B(ni);
    ISSUE128(Ag, 128, An, kn);
    ISSUE128(Bg, 0,   Bn, kn);
    if constexpr (NF == 4) ISSUE128(Bg, 128, Bn, kn);
    BAR; MFMAC(0); BAR;
    // P1: high B frags; prefetch A0(t+2) (current buf; A reads done in P0)
#pragma unroll
    for (int ni = NF / 2; ni < NF; ++ni) RD_B(ni);
    ISSUE128(Ag, 0, Ac, kn2);
    asm volatile("s_waitcnt vmcnt(1)" ::: "memory");  // t+1 fully landed
    BAR; MFMAC(NF / 2); BAR;
  }

  asm volatile("s_waitcnt vmcnt(0)" ::: "memory");   // drain clamped DMAs
  __syncthreads();

  // ---------------- epilogue ----------------
  if (MODE == 1) {
#pragma unroll
    for (int mi = 0; mi < 8; ++mi)
#pragma unroll
      for (int ni = 0; ni < NF; ++ni) {
        int gcol = n0 + wc * WN + ni * 16 + l15;
        float bv = bias[gcol];
#pragma unroll
        for (int i = 0; i < 4; ++i) {
          int grow = m0 + wr * 128 + mi * 16 + quad * 4 + i;
          out[(long)grow * EMB + gcol] = acc[mi][ni][i] + bv;
        }
      }
  } else {
    int which = n0 >> 10;   // tile lies entirely in Q, K, or V (1024%BN==0)
    if (which < 2) {
      bf16* dst = (which == 0) ? q : k;
      float scale = (which == 0) ? QSCALE : 1.0f;
#pragma unroll
      for (int mi = 0; mi < 8; ++mi)
#pragma unroll
        for (int ni = 0; ni < NF; ++ni) {
          int gcol = n0 + wc * WN + ni * 16 + l15;
          float bv = bias[gcol];
          int e = gcol & 1023, h = e >> 6, d = e & 63;
#pragma unroll
          for (int i = 0; i < 4; ++i) {
            int grow = m0 + wr * 128 + mi * 16 + quad * 4 + i;
            int b = grow >> 11, ss = grow & 2047;
            dst[(((long)b * NH + h) * SEQ + ss) * HD + d] =
                (bf16)((acc[mi][ni][i] + bv) * scale);
          }
        }
    } else {
      // V^T scatter (proven R6: WRITE_SIZE stays ideal, L2 absorbs)
#pragma unroll
      for (int mi = 0; mi < 8; ++mi)
#pragma unroll
        for (int ni = 0; ni < NF; ++ni) {
          int gcol = n0 + wc * WN + ni * 16 + l15;
          float bv = bias[gcol];
          int e = gcol & 1023, h = e >> 6, d = e & 63;
#pragma unroll
          for (int i = 0; i < 4; ++i) {
            int grow = m0 + wr * 128 + mi * 16 + quad * 4 + i;
            int b = grow >> 11, ss = grow & 2047;
            v[(((long)b * NH + h) * HD + d) * SEQ + ss] =
                (bf16)(acc[mi][ni][i] + bv);
          }
        }
    }
  }
#undef LDSA
#undef LDSB
#undef ISSUE128
#undef RD_A
#undef RD_B
#undef MFMAC
}

// ---------------- flash attention ----------------
// 1D grid 512 blocks; block 256 = 4 waves x 32 q-rows = 128-row strip.
// Decode: xcd=L&7, a=L>>3; head = xcd + 8*(a&7)  -> all 8 blocks of a head
// share L%8 (same XCD under round-robin dispatch; per-XCD L2 holds the head's
// 512 KB K/V). strip = a>>3; block runs strips st and 15-st (18 tiles each).
// 64-key tiles staged ONCE per block (shared by 4 waves) via global_load_lds.
#define LDP 72   // P row stride (elems): conflict-free, 16B-aligned

__global__ __launch_bounds__(256, 2) void attn(
    const bf16* __restrict__ Q, const bf16* __restrict__ K,
    const bf16* __restrict__ Vt, bf16* __restrict__ Y)
{
  __shared__ __align__(16) bf16 Kl[64 * 64];        // 8 KB
  __shared__ __align__(16) bf16 Vl[64 * 64];        // 8 KB
  __shared__ __align__(16) bf16 Pl[4][32 * LDP];    // 18 KB, per-wave
  int L = blockIdx.x;
  int a = L >> 3;
  int hd = (L & 7) + 8 * (a & 7);
  int st = a >> 3;
  int b = hd >> 4, h = hd & 15;
  const bf16* Qp  = Q  + (((long)b * NH + h) * SEQ) * HD;
  const bf16* Kp  = K  + (((long)b * NH + h) * SEQ) * HD;
  const bf16* Vtp = Vt + (((long)b * NH + h) * HD) * SEQ;
  int t = threadIdx.x, wave = t >> 6, lane = t & 63;
  int l15 = lane & 15, quad = lane >> 4;

#pragma unroll 1
  for (int pass = 0; pass < 2; ++pass) {
    int q0 = (pass == 0) ? st * 128 : (SEQ - 128) - st * 128;
    int wq0 = q0 + wave * 32;

    // Q fragments: m-frag m covers rows wq0+m*16 .. +15; k split 0/32
    bf16x8 qf[2][2];
#pragma unroll
    for (int m = 0; m < 2; ++m) {
      const bf16* qrow = Qp + (long)(wq0 + m * 16 + l15) * HD + quad * 8;
      qf[m][0] = *(const bf16x8*)(qrow);
      qf[m][1] = *(const bf16x8*)(qrow + 32);
    }
    float lrow[2][4] = {};
    f32x4 oacc[2][4] = {};

    int ntiles = q0 / 64 + 2;     // block's 128 rows need tiles through q0+127
#pragma unroll 1
    for (int kt = 0; kt < ntiles; ++kt) {
      int k0 = kt * 64;
      __syncthreads();
      // stage K [key][d], V^T [d][key]: unit row*8+u holds chunk u^(row&7)
#pragma unroll
      for (int it = 0; it < 2; ++it) {
        int cu = it * 256 + t;
        int row = cu >> 3, u = cu & 7;
        ld_lds16(&Kp[(long)(k0 + row) * HD + ((u ^ (row & 7)) * 8)],
                 &Kl[(it * 256 + wave * 64) * 8]);
        ld_lds16(&Vtp[(long)row * SEQ + k0 + ((u ^ (row & 7)) * 8)],
                 &Vl[(it * 256 + wave * 64) * 8]);
      }
      __syncthreads();
      if (k0 > wq0 + 31) continue;   // wave's rows all masked for this tile

      // scores: S[32q x 64k]; kfr register-shared across both m-frags
      f32x4 sc[2][4] = {};
#pragma unroll
      for (int kk = 0; kk < 2; ++kk) {
#pragma unroll
        for (int ni = 0; ni < 4; ++ni) {
          int r = ni * 16 + l15, u = kk * 4 + quad;
          bf16x8 kfr = *(const bf16x8*)(&Kl[r * 64 + ((u ^ (r & 7)) * 8)]);
          sc[0][ni] = __builtin_amdgcn_mfma_f32_16x16x32_bf16(qf[0][kk], kfr, sc[0][ni], 0, 0, 0);
          sc[1][ni] = __builtin_amdgcn_mfma_f32_16x16x32_bf16(qf[1][kk], kfr, sc[1][ni], 0, 0, 0);
        }
      }

      bool full = (k0 + 63 <= wq0);   // wave-uniform (min row = wq0)
#pragma unroll
      for (int m = 0; m < 2; ++m) {
#pragma unroll
        for (int i = 0; i < 4; ++i) {
          int qr = wq0 + m * 16 + quad * 4 + i;
          float e[4];
#pragma unroll
          for (int ni = 0; ni < 4; ++ni) {
            float x = sc[m][ni][i];
            if (!full) x = (k0 + ni * 16 + l15 <= qr) ? x : -1e30f;
            e[ni] = __builtin_amdgcn_exp2f(x);
          }
          lrow[m][i] += (e[0] + e[1]) + (e[2] + e[3]);
          int prow = (m * 16 + quad * 4 + i) * LDP;
#pragma unroll
          for (int ni = 0; ni < 4; ++ni)
            Pl[wave][prow + ni * 16 + l15] = (bf16)e[ni];
        }
      }
      asm volatile("s_waitcnt lgkmcnt(0)" ::: "memory");
      // PV: P[32x64] @ V[64x64]; vf register-shared across both m-frags
#pragma unroll
      for (int kk = 0; kk < 2; ++kk) {
        int kbase = kk * 32 + quad * 8;
        bf16x8 pf0 = *(const bf16x8*)(&Pl[wave][(l15) * LDP + kbase]);
        bf16x8 pf1 = *(const bf16x8*)(&Pl[wave][(16 + l15) * LDP + kbase]);
#pragma unroll
        for (int ni = 0; ni < 4; ++ni) {
          int dd = ni * 16 + l15, u = kk * 4 + quad;
          bf16x8 vf = *(const bf16x8*)(&Vl[dd * 64 + ((u ^ (dd & 7)) * 8)]);
          oacc[0][ni] = __builtin_amdgcn_mfma_f32_16x16x32_bf16(pf0, vf, oacc[0][ni], 0, 0, 0);
          oacc[1][ni] = __builtin_amdgcn_mfma_f32_16x16x32_bf16(pf1, vf, oacc[1][ni], 0, 0, 0);
        }
      }
    }
    // epilogue: reduce l across the 16-lane column groups, write Y bf16
#pragma unroll
    for (int m = 0; m < 2; ++m) {
#pragma unroll
      for (int i = 0; i < 4; ++i) {
        float rs = lrow[m][i];
#pragma unroll
        for (int off = 8; off; off >>= 1) rs += __shfl_xor(rs, off, 16);
        float inv = 1.0f / rs;
        int qr = wq0 + m * 16 + quad * 4 + i;
        bf16* dst = Y + ((long)(b * SEQ + qr)) * EMB + h * HD;
#pragma unroll
        for (int ni = 0; ni < 4; ++ni)
          dst[ni * 16 + l15] = (bf16)(oacc[m][ni][i] * inv);
      }
    }
  }
}

extern "C" void kernel_launch(void* const* d_in, const int* in_sizes, int n_in,
                              void* d_out, int out_size, void* d_ws, size_t ws_size,
                              hipStream_t stream) {
  const float* x      = (const float*)d_in[0];
  const float* W_attn = (const float*)d_in[1];
  const float* b_attn = (const float*)d_in[2];
  const float* W_proj = (const float*)d_in[3];
  const float* b_proj = (const float*)d_in[4];
  float* out = (float*)d_out;
  char* ws = (char*)d_ws;
  bf16* xb  = (bf16*)(ws);                 // 16.78 MB
  bf16* WaT = (bf16*)(ws + 16777216);      //  6.29 MB
  bf16* WpT = (bf16*)(ws + 23068672);      //  2.10 MB
  bf16* Qb  = (bf16*)(ws + 25165824);      // 16.78 MB (pre-scaled)
  bf16* Kb  = (bf16*)(ws + 41943040);      // 16.78 MB
  bf16* Vtb = (bf16*)(ws + 58720256);      // 16.78 MB (transposed [b,h,d,s])
  bf16* Yb  = (bf16*)(ws + 75497472);      // 16.78 MB

  cvt_f32_bf16<<<8192, 256, 0, stream>>>(x, xb, BATCH * SEQ * EMB);
  transpose_cvt2<<<dim3(128, 32), 256, 0, stream>>>(W_attn, W_proj, WaT, WpT);
  gemm8p<0, 4><<<384, 512, 0, stream>>>(xb, WaT, b_attn, Qb, Kb, Vtb, nullptr);
  attn<<<512, 256, 0, stream>>>(Qb, Kb, Vtb, Yb);
  gemm8p<1, 2><<<256, 512, 0, stream>>>(Yb, WpT, b_proj,
                                        nullptr, nullptr, nullptr, out);
}

// Round 3
// 256.262 us; speedup vs baseline: 1.0587x; 1.0587x over previous
//
#include <hip/hip_runtime.h>

// CausalSelfAttention: x[4,2048,1024] fp32 -> out fp32
// Pipeline (all bf16 MFMA, fp32 accum):
//  1) cvt x -> bf16            2) transpose+cvt W_attn & W_proj -> bf16 [N][K]
//  3) gemm8p<0,4> (256x256 tile, BK=32, 2-phase/tile counted-vmcnt schedule)
//     -> Q (pre-scaled by 0.125*log2e), K, V TRANSPOSED [b,h,d,s] (scatter)
//  4) flash attention: 128 q-rows/block (4 waves x 32), XCD head-affinity
//     swizzle, fixed-max softmax (P = 2^s), K/Vt direct-to-LDS w/ XOR swizzle.
//  5) gemm_bt<64> (128x64 tile, 1024 blocks, 3/CU) + bias -> out fp32
//
// R3 post-mortem of R2 (271us, QKV 85.6us @ MfmaUtil 24%, 4.7M bank conflicts):
//  (a) BK=32 made LDS rows 64B (16 banks); old u^(r&3) XOR left reads 4-way
//      conflicted: bank-quad q=(quad^(r&3))+4*(r&1) hits only 4 of 8 quads.
//      FIX: rotation swizzle. Writer puts logical chunk ((t&3)-((t>>3)&3))&3
//      in slot t&3; reader uses slot (quad+(l15>>1))&3. Bank-quad
//      ((quad+(l15>>1))&3)+4*(l15&1) covers all 8 quads exactly 2x over 16
//      lanes -> 2-way = free (m136). LDS/MFMA per K-tile/CU: 750 vs 640 cyc,
//      so de-conflicting LDS directly lifts MfmaUtil.
//  (b) proj as 256-block phase-gemm = 1 block/CU, no TLP to cover vmcnt waits
//      -> ~80us (vs ~35 old). REVERTED to R0's gemm_bt<64> (known ~35us).
// QKV schedule (guide T3+T4+T5, counted vmcnt, never 0 in loop):
//  - 8 waves (2M x 4N), per-wave 128x64 out, acc[8][4] f32x4
//  - LDS: A[2][256][32] + B[2][256][32] bf16 = 64KB static
//  - per K-tile: P0 {RD_A x8, RD_B x2, issue A1/B0/B1(t+1), BAR, setprio1,
//    16 MFMA, setprio0, BAR}  P1 {RD_B x2, issue A0(t+2), vmcnt(1), BAR,
//    setprio1, 16 MFMA, setprio0, BAR}
//  - overwrite safety: every ds_read consumed by MFMA in its own phase
//    (compiler lgkmcnt) -> done before trailing barrier; prefetch issues are
//    in a later phase. Tail issues clamped (identical-data reload, benign).
// MFMA 16x16x32 bf16 layouts (HW-verified per guide):
//   A: a[j] = A[m=lane&15][k=quad*8+j]  (quad=lane>>4)
//   B: b[j] = B[k=quad*8+j][n=lane&15]  (from Bt[n][k] read at row n)
//   C/D: c[i] = D[row=quad*4+i][col=lane&15]

#define BATCH 4
#define SEQ   2048
#define EMB   1024
#define NH    16
#define HD    64

typedef __bf16 bf16;
typedef __bf16 bf16x8 __attribute__((ext_vector_type(8)));
typedef float  f32x4  __attribute__((ext_vector_type(4)));

// direct global->LDS 16B copy: LDS dest is wave-uniform base + lane*16
__device__ __forceinline__ void ld_lds16(const void* g, void* l) {
  __builtin_amdgcn_global_load_lds(
      (const __attribute__((address_space(1))) void*)g,
      (__attribute__((address_space(3))) void*)l, 16, 0, 0);
}

// ---------------- convert fp32 -> bf16 ----------------
__global__ void cvt_f32_bf16(const float* __restrict__ in, bf16* __restrict__ out, int n) {
  int i = (blockIdx.x * blockDim.x + threadIdx.x) * 4;
  if (i + 3 < n) {
    float4 v = *(const float4*)(in + i);
    bf16 o0 = (bf16)v.x, o1 = (bf16)v.y, o2 = (bf16)v.z, o3 = (bf16)v.w;
    out[i] = o0; out[i+1] = o1; out[i+2] = o2; out[i+3] = o3;
  }
}

// ---------------- transpose + convert both weights (one launch) ----------------
__global__ void transpose_cvt2(const float* __restrict__ Wa, const float* __restrict__ Wp,
                               bf16* __restrict__ WaT, bf16* __restrict__ WpT) {
  __shared__ float tile[32][33];
  int bx = blockIdx.x;
  const float* W; bf16* WT; int N;
  if (bx < 96) { W = Wa; WT = WaT; N = 3072; }
  else         { W = Wp; WT = WpT; N = 1024; bx -= 96; }
  int n0 = bx * 32, k0 = blockIdx.y * 32;
  int tx = threadIdx.x & 31, ty = threadIdx.x >> 5;
#pragma unroll
  for (int r = 0; r < 4; r++) {
    int k = k0 + ty + r * 8;
    tile[ty + r * 8][tx] = W[(long)k * N + n0 + tx];
  }
  __syncthreads();
#pragma unroll
  for (int r = 0; r < 4; r++) {
    int n = n0 + ty + r * 8;
    WT[(long)n * EMB + k0 + tx] = (bf16)tile[tx][ty + r * 8];
  }
}

#define QSCALE 0.18033688f   // (1/8) * log2(e)

// ---------------- 256x256 phase-pipelined QKV GEMM ----------------
// A[8192][1024] bf16 x Bt[3072][1024] bf16 + bias -> Q/K/V. Grid 384 x 512thr.
__global__ __launch_bounds__(512, 2) void gemm8p(
    const bf16* __restrict__ A, const bf16* __restrict__ Bt,
    const float* __restrict__ bias,
    bf16* __restrict__ q, bf16* __restrict__ k, bf16* __restrict__ v)
{
  __shared__ __align__(16) bf16 lds[3 * 16384];   // A[2][8192] | B[2][8192]
  int lin = blockIdx.x;
  int xcd = lin & 7, s = lin >> 3;
  int by = xcd * 4 + (s & 3);        // XCD-affine row strips
  int bx = s >> 2;
  int m0 = by * 256, n0 = bx * 256;
  int t = threadIdx.x;
  int wid = t >> 6, lane = t & 63;
  int l15 = lane & 15, quad = lane >> 4;
  int wr = wid >> 2, wc = wid & 3;   // wave tile: rows wr*128.., cols wc*64..

  const bf16* Ag = A + (long)m0 * EMB;
  const bf16* Bg = Bt + (long)n0 * EMB;

  f32x4 acc[8][4] = {};
  bf16x8 af[8], bfr[4];
  constexpr int NT = EMB / 32;       // 32 K-tiles
  // physical chunk slot for all frag reads (rotation swizzle; see header)
  int ph8 = ((quad + (l15 >> 1)) & 3) * 8;

#define LDSA(b) (lds + (b) * 8192)
#define LDSB(b) (lds + 16384 + (b) * 8192)

  // stage a 128-row x 32-col half-tile: 1 gload_lds per thread.
  // LDS dest linear; slot p=t&3 receives logical chunk (p-(r>>1))&3.
#define ISSUE128(gbase, rowoff, ldst, ktt)                                     \
  { int r_ = (rowoff) + (t >> 2);                                              \
    int g_ = ((t & 3) - ((t >> 3) & 3)) & 3;                                   \
    ld_lds16(&(gbase)[(long)r_ * EMB + (ktt) + g_ * 8],                        \
             (ldst) + ((rowoff) + wid * 16) * 32); }

#define RD_A(mi) { int r_ = wr * 128 + (mi) * 16 + l15;                        \
    af[mi] = *(const bf16x8*)&Ab[r_ * 32 + ph8]; }
#define RD_B(ni) { int r_ = wc * 64 + (ni) * 16 + l15;                         \
    bfr[ni] = *(const bf16x8*)&Bb[r_ * 32 + ph8]; }

#define FENCE asm volatile("" ::: "memory")
#define BAR   { FENCE; __builtin_amdgcn_s_barrier(); FENCE; }

#define MFMAC(nlo)                                                             \
  { __builtin_amdgcn_s_setprio(1);                                             \
    _Pragma("unroll") for (int mi_ = 0; mi_ < 8; ++mi_)                        \
      _Pragma("unroll") for (int nj_ = 0; nj_ < 2; ++nj_)                      \
        acc[mi_][(nlo) + nj_] = __builtin_amdgcn_mfma_f32_16x16x32_bf16(       \
            af[mi_], bfr[(nlo) + nj_], acc[mi_][(nlo) + nj_], 0, 0, 0);        \
    __builtin_amdgcn_s_setprio(0); }

  // prologue: tile0 complete + A-half0(tile1) in flight
  ISSUE128(Ag, 0,   LDSA(0), 0);
  ISSUE128(Ag, 128, LDSA(0), 0);
  ISSUE128(Bg, 0,   LDSB(0), 0);
  ISSUE128(Bg, 128, LDSB(0), 0);
  ISSUE128(Ag, 0,   LDSA(1), 32);
  asm volatile("s_waitcnt vmcnt(1)" ::: "memory");
  BAR;

#pragma unroll 2
  for (int tt = 0; tt < NT; ++tt) {
    const bf16* Ab = LDSA(tt & 1);
    const bf16* Bb = LDSB(tt & 1);
    bf16* An = LDSA((tt + 1) & 1);
    bf16* Bn = LDSB((tt + 1) & 1);
    bf16* Ac = LDSA(tt & 1);                         // A0(t+2): (tt+2)&1==tt&1
    int kn  = (tt + 1 < NT ? tt + 1 : NT - 1) * 32;  // clamped at tail:
    int kn2 = (tt + 2 < NT ? tt + 2 : NT - 1) * 32;  // dummy identical reload

    // P0: all A frags + low B frags; prefetch A1/B0/B1(t+1) (other buffer)
#pragma unroll
    for (int mi = 0; mi < 8; ++mi) RD_A(mi);
    RD_B(0); RD_B(1);
    ISSUE128(Ag, 128, An, kn);
    ISSUE128(Bg, 0,   Bn, kn);
    ISSUE128(Bg, 128, Bn, kn);
    BAR; MFMAC(0); BAR;
    // P1: high B frags; prefetch A0(t+2) (current buf; A reads done in P0)
    RD_B(2); RD_B(3);
    ISSUE128(Ag, 0, Ac, kn2);
    asm volatile("s_waitcnt vmcnt(1)" ::: "memory");  // t+1 fully landed
    BAR; MFMAC(2); BAR;
  }

  asm volatile("s_waitcnt vmcnt(0)" ::: "memory");   // drain clamped DMAs
  __syncthreads();

  // ---------------- epilogue: Q (scaled) / K / V^T scatter ----------------
  int which = n0 >> 10;   // tile lies entirely in Q, K, or V
  if (which < 2) {
    bf16* dst = (which == 0) ? q : k;
    float scale = (which == 0) ? QSCALE : 1.0f;
#pragma unroll
    for (int mi = 0; mi < 8; ++mi)
#pragma unroll
      for (int ni = 0; ni < 4; ++ni) {
        int gcol = n0 + wc * 64 + ni * 16 + l15;
        float bv = bias[gcol];
        int e = gcol & 1023, h = e >> 6, d = e & 63;
#pragma unroll
        for (int i = 0; i < 4; ++i) {
          int grow = m0 + wr * 128 + mi * 16 + quad * 4 + i;
          int b = grow >> 11, ss = grow & 2047;
          dst[(((long)b * NH + h) * SEQ + ss) * HD + d] =
              (bf16)((acc[mi][ni][i] + bv) * scale);
        }
      }
  } else {
    // V^T scatter (proven: WRITE_SIZE stays ideal, L2 absorbs)
#pragma unroll
    for (int mi = 0; mi < 8; ++mi)
#pragma unroll
      for (int ni = 0; ni < 4; ++ni) {
        int gcol = n0 + wc * 64 + ni * 16 + l15;
        float bv = bias[gcol];
        int e = gcol & 1023, h = e >> 6, d = e & 63;
#pragma unroll
        for (int i = 0; i < 4; ++i) {
          int grow = m0 + wr * 128 + mi * 16 + quad * 4 + i;
          int b = grow >> 11, ss = grow & 2047;
          v[(((long)b * NH + h) * HD + d) * SEQ + ss] =
              (bf16)(acc[mi][ni][i] + bv);
        }
      }
  }
#undef LDSA
#undef LDSB
#undef ISSUE128
#undef RD_A
#undef RD_B
#undef MFMAC
}

// ---------------- proj GEMM (R0 known-good): 128x64 tile, 3 blocks/CU ------
__global__ __launch_bounds__(256, 3) void gemm_proj(
    const bf16* __restrict__ A, const bf16* __restrict__ Bt,
    const float* __restrict__ bias, float* __restrict__ out)
{
  __shared__ __align__(16) bf16 Al[128 * 64];
  __shared__ __align__(16) bf16 Bl[64 * 64];
  int lin = blockIdx.x;
  int xcd = lin & 7, s = lin >> 3;
  int bx = s >> 3, by = xcd * 8 + (s & 7);
  int m0 = by * 128;
  int n0 = bx * 64;
  int t = threadIdx.x;
  int wave = t >> 6, lane = t & 63;
  int l15 = lane & 15, quad = lane >> 4;
  int wm = (wave & 1) * 64, wn = (wave >> 1) * 32;

  f32x4 acc[4][2] = {};

  for (int kt = 0; kt < EMB; kt += 64) {
    __syncthreads();
#pragma unroll
    for (int it = 0; it < 4; ++it) {         // A: 128 rows x 8 units
      int c = it * 256 + t;
      int row = c >> 3, u = c & 7;
      ld_lds16(&A[(long)(m0 + row) * EMB + kt + ((u ^ (row & 7)) * 8)],
               &Al[(it * 256 + wave * 64) * 8]);
    }
    {
      int c = t;                              // B: 64 rows x 8 units
      int row = c >> 3, u = c & 7;
      ld_lds16(&Bt[(long)(n0 + row) * EMB + kt + ((u ^ (row & 7)) * 8)],
               &Bl[(wave * 64) * 8]);
      c = 256 + t;
      row = c >> 3; u = c & 7;
      ld_lds16(&Bt[(long)(n0 + row) * EMB + kt + ((u ^ (row & 7)) * 8)],
               &Bl[(256 + wave * 64) * 8]);
    }
    __syncthreads();
#pragma unroll
    for (int ks = 0; ks < 2; ++ks) {
      bf16x8 af[4], bfr[2];
#pragma unroll
      for (int i = 0; i < 4; ++i) {
        int r = wm + i * 16 + l15;
        af[i] = *(const bf16x8*)(&Al[r * 64 + (((ks * 4 + quad) ^ (r & 7)) * 8)]);
      }
#pragma unroll
      for (int i = 0; i < 2; ++i) {
        int r = wn + i * 16 + l15;
        bfr[i] = *(const bf16x8*)(&Bl[r * 64 + (((ks * 4 + quad) ^ (r & 7)) * 8)]);
      }
#pragma unroll
      for (int mi = 0; mi < 4; ++mi)
#pragma unroll
        for (int ni = 0; ni < 2; ++ni)
          acc[mi][ni] = __builtin_amdgcn_mfma_f32_16x16x32_bf16(af[mi], bfr[ni], acc[mi][ni], 0, 0, 0);
    }
  }

#pragma unroll
  for (int mi = 0; mi < 4; ++mi)
#pragma unroll
    for (int ni = 0; ni < 2; ++ni) {
      int gcol = n0 + wn + ni * 16 + l15;
      float bv = bias[gcol];
#pragma unroll
      for (int i = 0; i < 4; ++i) {
        int grow = m0 + wm + mi * 16 + quad * 4 + i;
        out[(long)grow * EMB + gcol] = acc[mi][ni][i] + bv;
      }
    }
}

// ---------------- flash attention ----------------
// 1D grid 512 blocks; block 256 = 4 waves x 32 q-rows = 128-row strip.
// Decode: xcd=L&7, a=L>>3; head = xcd + 8*(a&7)  -> all 8 blocks of a head
// share L%8 (same XCD under round-robin dispatch; per-XCD L2 holds the head's
// 512 KB K/V). strip = a>>3; block runs strips st and 15-st (18 tiles each).
// 64-key tiles staged ONCE per block (shared by 4 waves) via global_load_lds.
#define LDP 72   // P row stride (elems): conflict-free, 16B-aligned

__global__ __launch_bounds__(256, 2) void attn(
    const bf16* __restrict__ Q, const bf16* __restrict__ K,
    const bf16* __restrict__ Vt, bf16* __restrict__ Y)
{
  __shared__ __align__(16) bf16 Kl[64 * 64];        // 8 KB
  __shared__ __align__(16) bf16 Vl[64 * 64];        // 8 KB
  __shared__ __align__(16) bf16 Pl[4][32 * LDP];    // 18 KB, per-wave
  int L = blockIdx.x;
  int a = L >> 3;
  int hd = (L & 7) + 8 * (a & 7);
  int st = a >> 3;
  int b = hd >> 4, h = hd & 15;
  const bf16* Qp  = Q  + (((long)b * NH + h) * SEQ) * HD;
  const bf16* Kp  = K  + (((long)b * NH + h) * SEQ) * HD;
  const bf16* Vtp = Vt + (((long)b * NH + h) * HD) * SEQ;
  int t = threadIdx.x, wave = t >> 6, lane = t & 63;
  int l15 = lane & 15, quad = lane >> 4;

#pragma unroll 1
  for (int pass = 0; pass < 2; ++pass) {
    int q0 = (pass == 0) ? st * 128 : (SEQ - 128) - st * 128;
    int wq0 = q0 + wave * 32;

    // Q fragments: m-frag m covers rows wq0+m*16 .. +15; k split 0/32
    bf16x8 qf[2][2];
#pragma unroll
    for (int m = 0; m < 2; ++m) {
      const bf16* qrow = Qp + (long)(wq0 + m * 16 + l15) * HD + quad * 8;
      qf[m][0] = *(const bf16x8*)(qrow);
      qf[m][1] = *(const bf16x8*)(qrow + 32);
    }
    float lrow[2][4] = {};
    f32x4 oacc[2][4] = {};

    int ntiles = q0 / 64 + 2;     // block's 128 rows need tiles through q0+127
#pragma unroll 1
    for (int kt = 0; kt < ntiles; ++kt) {
      int k0 = kt * 64;
      __syncthreads();
      // stage K [key][d], V^T [d][key]: unit row*8+u holds chunk u^(row&7)
#pragma unroll
      for (int it = 0; it < 2; ++it) {
        int cu = it * 256 + t;
        int row = cu >> 3, u = cu & 7;
        ld_lds16(&Kp[(long)(k0 + row) * HD + ((u ^ (row & 7)) * 8)],
                 &Kl[(it * 256 + wave * 64) * 8]);
        ld_lds16(&Vtp[(long)row * SEQ + k0 + ((u ^ (row & 7)) * 8)],
                 &Vl[(it * 256 + wave * 64) * 8]);
      }
      __syncthreads();
      if (k0 > wq0 + 31) continue;   // wave's rows all masked for this tile

      // scores: S[32q x 64k]; kfr register-shared across both m-frags
      f32x4 sc[2][4] = {};
#pragma unroll
      for (int kk = 0; kk < 2; ++kk) {
#pragma unroll
        for (int ni = 0; ni < 4; ++ni) {
          int r = ni * 16 + l15, u = kk * 4 + quad;
          bf16x8 kfr = *(const bf16x8*)(&Kl[r * 64 + ((u ^ (r & 7)) * 8)]);
          sc[0][ni] = __builtin_amdgcn_mfma_f32_16x16x32_bf16(qf[0][kk], kfr, sc[0][ni], 0, 0, 0);
          sc[1][ni] = __builtin_amdgcn_mfma_f32_16x16x32_bf16(qf[1][kk], kfr, sc[1][ni], 0, 0, 0);
        }
      }

      bool full = (k0 + 63 <= wq0);   // wave-uniform (min row = wq0)
#pragma unroll
      for (int m = 0; m < 2; ++m) {
#pragma unroll
        for (int i = 0; i < 4; ++i) {
          int qr = wq0 + m * 16 + quad * 4 + i;
          float e[4];
#pragma unroll
          for (int ni = 0; ni < 4; ++ni) {
            float x = sc[m][ni][i];
            if (!full) x = (k0 + ni * 16 + l15 <= qr) ? x : -1e30f;
            e[ni] = __builtin_amdgcn_exp2f(x);
          }
          lrow[m][i] += (e[0] + e[1]) + (e[2] + e[3]);
          int prow = (m * 16 + quad * 4 + i) * LDP;
#pragma unroll
          for (int ni = 0; ni < 4; ++ni)
            Pl[wave][prow + ni * 16 + l15] = (bf16)e[ni];
        }
      }
      asm volatile("s_waitcnt lgkmcnt(0)" ::: "memory");
      // PV: P[32x64] @ V[64x64]; vf register-shared across both m-frags
#pragma unroll
      for (int kk = 0; kk < 2; ++kk) {
        int kbase = kk * 32 + quad * 8;
        bf16x8 pf0 = *(const bf16x8*)(&Pl[wave][(l15) * LDP + kbase]);
        bf16x8 pf1 = *(const bf16x8*)(&Pl[wave][(16 + l15) * LDP + kbase]);
#pragma unroll
        for (int ni = 0; ni < 4; ++ni) {
          int dd = ni * 16 + l15, u = kk * 4 + quad;
          bf16x8 vf = *(const bf16x8*)(&Vl[dd * 64 + ((u ^ (dd & 7)) * 8)]);
          oacc[0][ni] = __builtin_amdgcn_mfma_f32_16x16x32_bf16(pf0, vf, oacc[0][ni], 0, 0, 0);
          oacc[1][ni] = __builtin_amdgcn_mfma_f32_16x16x32_bf16(pf1, vf, oacc[1][ni], 0, 0, 0);
        }
      }
    }
    // epilogue: reduce l across the 16-lane column groups, write Y bf16
#pragma unroll
    for (int m = 0; m < 2; ++m) {
#pragma unroll
      for (int i = 0; i < 4; ++i) {
        float rs = lrow[m][i];
#pragma unroll
        for (int off = 8; off; off >>= 1) rs += __shfl_xor(rs, off, 16);
        float inv = 1.0f / rs;
        int qr = wq0 + m * 16 + quad * 4 + i;
        bf16* dst = Y + ((long)(b * SEQ + qr)) * EMB + h * HD;
#pragma unroll
        for (int ni = 0; ni < 4; ++ni)
          dst[ni * 16 + l15] = (bf16)(oacc[m][ni][i] * inv);
      }
    }
  }
}

extern "C" void kernel_launch(void* const* d_in, const int* in_sizes, int n_in,
                              void* d_out, int out_size, void* d_ws, size_t ws_size,
                              hipStream_t stream) {
  const float* x      = (const float*)d_in[0];
  const float* W_attn = (const float*)d_in[1];
  const float* b_attn = (const float*)d_in[2];
  const float* W_proj = (const float*)d_in[3];
  const float* b_proj = (const float*)d_in[4];
  float* out = (float*)d_out;
  char* ws = (char*)d_ws;
  bf16* xb  = (bf16*)(ws);                 // 16.78 MB
  bf16* WaT = (bf16*)(ws + 16777216);      //  6.29 MB
  bf16* WpT = (bf16*)(ws + 23068672);      //  2.10 MB
  bf16* Qb  = (bf16*)(ws + 25165824);      // 16.78 MB (pre-scaled)
  bf16* Kb  = (bf16*)(ws + 41943040);      // 16.78 MB
  bf16* Vtb = (bf16*)(ws + 58720256);      // 16.78 MB (transposed [b,h,d,s])
  bf16* Yb  = (bf16*)(ws + 75497472);      // 16.78 MB

  cvt_f32_bf16<<<8192, 256, 0, stream>>>(x, xb, BATCH * SEQ * EMB);
  transpose_cvt2<<<dim3(128, 32), 256, 0, stream>>>(W_attn, W_proj, WaT, WpT);
  gemm8p<<<384, 512, 0, stream>>>(xb, WaT, b_attn, Qb, Kb, Vtb);
  attn<<<512, 256, 0, stream>>>(Qb, Kb, Vtb, Yb);
  gemm_proj<<<1024, 256, 0, stream>>>(Yb, WpT, b_proj, out);
}